// Round 16
// baseline (1247.981 us; speedup 1.0000x reference)
//
#include <hip/hip_runtime.h>
#include <math.h>

// GATv2 2-layer: N=50000, E=800000, HEADS=8, C=32, ODIM=256, IN_C=64
#define HEADS 8
#define CDIM 32
#define ODIM 256

typedef _Float16 h2 __attribute__((ext_vector_type(2)));
typedef _Float16 h4 __attribute__((ext_vector_type(4)));
typedef _Float16 h8v __attribute__((ext_vector_type(8)));
union H4 { h4 v; h2 p[2]; };   // edge kernel only (VGPR 20, proven no-spill)

#if __has_builtin(__builtin_amdgcn_fdot2)
#define FDOT2(a,b,c) __builtin_amdgcn_fdot2((a),(b),(c),false)
#else
static __device__ __forceinline__ float fdot2_sw(h2 a, h2 b, float c){
  return fmaf((float)a.x, (float)b.x, fmaf((float)a.y, (float)b.y, c));
}
#define FDOT2(a,b,c) fdot2_sw((a),(b),(c))
#endif

// 8-wide fp16 dot. Operands arrive as float4 (R12-proven SROA-safe array
// element type; R13/R15: <8 x half> arrays get stack-allocated). bit_cast is
// SSA-only, byte-layout identical.
static __device__ __forceinline__ float dot8f(float4 af, float4 bf, float c){
  h8v a = __builtin_bit_cast(h8v, af);
  h8v b = __builtin_bit_cast(h8v, bf);
  c = FDOT2(__builtin_shufflevector(a,a,0,1), __builtin_shufflevector(b,b,0,1), c);
  c = FDOT2(__builtin_shufflevector(a,a,2,3), __builtin_shufflevector(b,b,2,3), c);
  c = FDOT2(__builtin_shufflevector(a,a,4,5), __builtin_shufflevector(b,b,4,5), c);
  c = FDOT2(__builtin_shufflevector(a,a,6,7), __builtin_shufflevector(b,b,6,7), c);
  return c;
}

__device__ __forceinline__ float lrelu(float v, float s){ return fmaxf(v, s*v); }

// ---- fused single-kernel scan (replaces block_sum + scan_bsums + local_scan)
// Chained aggregate publish + full lookback. flags[b] starts at -1 (memset
// 0xFF); the published word IS the aggregate -> no ordering hazard. 196
// blocks <= 256 CUs -> all co-resident; publish precedes wait -> no deadlock.
__global__ void scan_fused_kernel(const int* __restrict__ counts,
                                  int* __restrict__ indptr,
                                  int* __restrict__ flags, int n){
  __shared__ int s[256];
  __shared__ int ws[4];
  int t = threadIdx.x;
  int b = blockIdx.x;
  int i = b*256 + t;
  int v = (i < n) ? counts[i] : 0;
  s[t] = v;
  __syncthreads();
  for (int off=1; off<256; off<<=1){
    int u = (t >= off) ? s[t-off] : 0;
    __syncthreads();
    s[t] += u;
    __syncthreads();
  }
  if (t == 255) atomicExch(&flags[b], s[255]);   // publish block aggregate
  int pre = 0;
  if (t < b){                                     // b <= 195 < 256
    int f;
    do { f = __atomic_load_n((const int*)&flags[t], __ATOMIC_RELAXED); } while (f < 0);
    pre = f;
  }
#pragma unroll
  for (int off=1; off<64; off<<=1) pre += __shfl_xor(pre, off);
  if ((t & 63) == 0) ws[t >> 6] = pre;
  __syncthreads();
  int total_prev = ws[0]+ws[1]+ws[2]+ws[3];
  int excl = total_prev + s[t] - v;
  if (i < n) indptr[i] = excl;
  if (i == n-1) indptr[n] = excl + v;
}

// atomic-free scatter: csr[indptr[d] + rank] = s. Ranks per dst are a
// permutation of 0..cnt-1 -> csr[beg,end) fully written (poison-proof).
__global__ void scatter_kernel(const int* __restrict__ src, const int* __restrict__ dst,
                               const int* __restrict__ rank, const int* __restrict__ indptr,
                               int* __restrict__ csr_src, int e){
  int i = blockIdx.x*256 + threadIdx.x;
  if (i < e){
    int r = rank[i];
    if (r >= 0){
      int d = dst[i];
      csr_src[indptr[d] + r] = src[i];
    }
  }
}

// ---------------- dense GEMM: out[n,o] = sum_k X[n,k]*W[o,k] + b[o] ----------------
// fp16-LDS + v_dot2_f32_f16. fp16 LDS halves ds_read count (8 vals per b128),
// fdot2 halves VALU issue (2 MAC/instr). Operands staged through float4
// arrays (register-resident, R12-proven) and bit_cast to h8v at the dot.
// LDS 36KB, (256,3) -> 3 blocks/CU. Block = 128 nodes x 64 outputs,
// micro 8x4x{l,r}. Both outputs fp16. FUSE_COUNT: y==0,x<96 runs CSR
// count+rank concurrently (dispatch-first, no-op backfill).
template<int K, bool FUSE_COUNT>
__global__ __launch_bounds__(256, 3) void gemm_kernel(const float* __restrict__ X,
    const float* __restrict__ Wl, const float* __restrict__ bl,
    const float* __restrict__ Wr, const float* __restrict__ br,
    _Float16* __restrict__ outl, _Float16* __restrict__ outr, int n,
    const int* __restrict__ src, const int* __restrict__ dst,
    int* __restrict__ counts, int* __restrict__ rank, int e){
  if (FUSE_COUNT && blockIdx.y == 0){
    const int CB = 96;
    if (blockIdx.x < CB){
      int stride = CB*256;
      for (int i = blockIdx.x*256 + threadIdx.x; i < e; i += stride){
        int s = src[i], d = dst[i];
        int r = -1;
        if (s != d) r = atomicAdd(counts + d, 1);   // src==dst masked (PyG removes)
        rank[i] = r;
      }
    }
    return;
  }
  const int KP = K + 8;                       // halves; rows 16B-aligned
  __shared__ _Float16 xt[128*(K+8)];
  __shared__ _Float16 wt[2][64*(K+8)];
  int t = threadIdx.x;
  int n0 = blockIdx.x*128;
  int o0 = (FUSE_COUNT ? (blockIdx.y-1) : blockIdx.y)*64;

  auto cvt8 = [](float4 a, float4 b)->h8v{
    h8v hv;
    hv[0]=(_Float16)a.x; hv[1]=(_Float16)a.y; hv[2]=(_Float16)a.z; hv[3]=(_Float16)a.w;
    hv[4]=(_Float16)b.x; hv[5]=(_Float16)b.y; hv[6]=(_Float16)b.z; hv[7]=(_Float16)b.w;
    return hv;
  };

  for (int idx = t; idx < 128*(K/8); idx += 256){
    int row = idx/(K/8), c = (idx%(K/8))*8;
    int node = n0 + row; if (node >= n) node = n-1;   // clamp; stores guarded
    float4 a = *(const float4*)(X + (size_t)node*K + c);
    float4 b = *(const float4*)(X + (size_t)node*K + c + 4);
    *(h8v*)(xt + row*KP + c) = cvt8(a, b);
  }
  for (int idx = t; idx < 64*(K/8); idx += 256){
    int row = idx/(K/8), c = (idx%(K/8))*8;
    float4 a = *(const float4*)(Wl + (size_t)(o0+row)*K + c);
    float4 b = *(const float4*)(Wl + (size_t)(o0+row)*K + c + 4);
    *(h8v*)(wt[0] + row*KP + c) = cvt8(a, b);
    a = *(const float4*)(Wr + (size_t)(o0+row)*K + c);
    b = *(const float4*)(Wr + (size_t)(o0+row)*K + c + 4);
    *(h8v*)(wt[1] + row*KP + c) = cvt8(a, b);
  }
  __syncthreads();

  int og = t & 15;          // outputs o0 + og + 16j  (j<4)
  int ng = t >> 4;          // nodes   n0 + ng + 16i  (i<8)
  float accl[8][4] = {{0.f}}, accr[8][4] = {{0.f}};

#pragma unroll
  for (int kk = 0; kk < K; kk += 8){
    float4 xv[8], wl[4], wr[4];
#pragma unroll
    for (int i=0;i<8;i++) xv[i] = *(const float4*)(xt + (ng+16*i)*KP + kk);
#pragma unroll
    for (int j=0;j<4;j++){
      wl[j] = *(const float4*)(wt[0] + (og+16*j)*KP + kk);
      wr[j] = *(const float4*)(wt[1] + (og+16*j)*KP + kk);
    }
#pragma unroll
    for (int i=0;i<8;i++){
#pragma unroll
      for (int j=0;j<4;j++){
        accl[i][j] = dot8f(xv[i], wl[j], accl[i][j]);
        accr[i][j] = dot8f(xv[i], wr[j], accr[i][j]);
      }
    }
  }

  float bvl[4], bvr[4];
#pragma unroll
  for (int j=0;j<4;j++){ bvl[j] = bl[o0+og+16*j]; bvr[j] = br[o0+og+16*j]; }
#pragma unroll
  for (int i=0;i<8;i++){
    int node = n0 + ng + 16*i;
    if (node < n){
      _Float16* pl = outl + (size_t)node*ODIM + o0 + og;
      _Float16* pr = outr + (size_t)node*ODIM + o0 + og;
#pragma unroll
      for (int j=0;j<4;j++){
        pl[16*j] = (_Float16)(accl[i][j] + bvl[j]);
        pr[16*j] = (_Float16)(accr[i][j] + bvr[j]);
      }
    }
  }
}

// ---------------- fused edge softmax + aggregate, one wave per node ----------------
// R6-proven memory structure (1 edge/iter, depth-2 guarded prefetch, h4/lane
// coalesced 512B/wave) + packed-fp16 score path (R10/R11-proven).
__global__ __launch_bounds__(256) void edge_kernel(
    const _Float16* __restrict__ xl, const _Float16* __restrict__ xr,
    const float* __restrict__ att, const float* __restrict__ bias,
    const int* __restrict__ indptr, const int* __restrict__ csr_src,
    float* __restrict__ out, int n, int act)
{
  int wid = blockIdx.x*4 + (threadIdx.x >> 6);
  if (wid >= n) return;
  int lane = threadIdx.x & 63;
  const float LOG2E = 1.44269504088896341f;

  float4 attf = *(const float4*)(att + 4*lane);
  h2 at0 = (h2){(_Float16)(attf.x*LOG2E), (_Float16)(attf.y*LOG2E)};
  h2 at1 = (h2){(_Float16)(attf.z*LOG2E), (_Float16)(attf.w*LOG2E)};
  const h2 c02 = {(_Float16)0.2f, (_Float16)0.2f};

  H4 xrh; xrh.v = *(const h4*)(xr + (size_t)wid*ODIM + 4*lane);
  H4 self; self.v = *(const h4*)(xl + (size_t)wid*ODIM + 4*lane);

  auto score = [&](const H4& c)->float{
    h2 t0 = c.p[0] + xrh.p[0];
    h2 t1 = c.p[1] + xrh.p[1];
    h2 q0 = __builtin_elementwise_max(t0, t0 * c02);
    h2 q1 = __builtin_elementwise_max(t1, t1 * c02);
    float d = FDOT2(q0, at0, FDOT2(q1, at1, 0.f));
    d += __shfl_xor(d, 1);   // reduce over the 8 lanes of this head
    d += __shfl_xor(d, 2);
    d += __shfl_xor(d, 4);
    return d;
  };

  // self-loop seeds the accumulator
  float w0 = exp2f(score(self));
  float denom = w0;
  float4 acc;
  acc.x = w0 * (float)self.v.x;
  acc.y = w0 * (float)self.v.y;
  acc.z = w0 * (float)self.v.z;
  acc.w = w0 * (float)self.v.w;

  int beg = __builtin_amdgcn_readfirstlane(indptr[wid]);
  int end = __builtin_amdgcn_readfirstlane(indptr[wid+1]);
  int cnt = end - beg;
  H4 r0, r1;
  r0.v = (h4){}; r1.v = (h4){};
  if (cnt > 0){
    int s0 = __builtin_amdgcn_readfirstlane(csr_src[beg]);
    r0.v = *(const h4*)(xl + (size_t)s0*ODIM + 4*lane);
  }
  if (cnt > 1){
    int s1 = __builtin_amdgcn_readfirstlane(csr_src[beg+1]);
    r1.v = *(const h4*)(xl + (size_t)s1*ODIM + 4*lane);
  }
  for (int k = 0; k < cnt; ++k){
    H4 cur = r0; r0 = r1;
    if (k+2 < cnt){
      int s2 = __builtin_amdgcn_readfirstlane(csr_src[beg+k+2]);
      r1.v = *(const h4*)(xl + (size_t)s2*ODIM + 4*lane);   // prefetch 2 ahead
    }
    float pe = exp2f(score(cur));
    denom += pe;
    acc.x = fmaf(pe, (float)cur.v.x, acc.x);   // v_fma_mix (single-use cvt)
    acc.y = fmaf(pe, (float)cur.v.y, acc.y);
    acc.z = fmaf(pe, (float)cur.v.z, acc.z);
    acc.w = fmaf(pe, (float)cur.v.w, acc.w);
  }
  float inv = 1.f/denom;
  float vx = acc.x*inv, vy = acc.y*inv, vz = acc.z*inv, vw = acc.w*inv;
  // mean over heads: sum lanes {l, l^8, l^16, l^32}
  vx += __shfl_xor(vx, 8);  vx += __shfl_xor(vx, 16);  vx += __shfl_xor(vx, 32);
  vy += __shfl_xor(vy, 8);  vy += __shfl_xor(vy, 16);  vy += __shfl_xor(vy, 32);
  vz += __shfl_xor(vz, 8);  vz += __shfl_xor(vz, 16);  vz += __shfl_xor(vz, 32);
  vw += __shfl_xor(vw, 8);  vw += __shfl_xor(vw, 16);  vw += __shfl_xor(vw, 32);
  if (lane < 8){
    float4 bv = *(const float4*)(bias + 4*lane);
    float ox = vx*0.125f + bv.x;
    float oy = vy*0.125f + bv.y;
    float oz = vz*0.125f + bv.z;
    float ow = vw*0.125f + bv.w;
    if (act){
      ox = lrelu(ox, 0.01f); oy = lrelu(oy, 0.01f);
      oz = lrelu(oz, 0.01f); ow = lrelu(ow, 0.01f);
    }
    *(float4*)(out + (size_t)wid*CDIM + 4*lane) = make_float4(ox, oy, oz, ow);
  }
}

extern "C" void kernel_launch(void* const* d_in, const int* in_sizes, int n_in,
                              void* d_out, int out_size, void* d_ws, size_t ws_size,
                              hipStream_t stream){
  (void)n_in; (void)out_size; (void)ws_size;
  const float* x    = (const float*)d_in[0];
  const int*   ei   = (const int*)d_in[1];
  const float* W1l  = (const float*)d_in[2];
  const float* b1l  = (const float*)d_in[3];
  const float* W1r  = (const float*)d_in[4];
  const float* b1r  = (const float*)d_in[5];
  const float* att1 = (const float*)d_in[6];
  const float* bias1= (const float*)d_in[7];
  const float* W2l  = (const float*)d_in[8];
  const float* b2l  = (const float*)d_in[9];
  const float* W2r  = (const float*)d_in[10];
  const float* b2r  = (const float*)d_in[11];
  const float* att2 = (const float*)d_in[12];
  const float* bias2= (const float*)d_in[13];
  int n = in_sizes[0] / 64;   // 50000
  int e = in_sizes[1] / 2;    // 800000
  const int* src = ei;
  const int* dst = ei + e;

  char* ws = (char*)d_ws;
  size_t off = 0;
  auto alloc = [&](size_t bytes)->char*{
    char* p = ws + off; off += (bytes + 255) & ~(size_t)255; return p;
  };
  _Float16* xl  = (_Float16*)alloc((size_t)n*ODIM*2);  // 25.6 MB fp16
  _Float16* xr  = (_Float16*)alloc((size_t)n*ODIM*2);  // 25.6 MB fp16
  float* h      = (float*)alloc((size_t)n*CDIM*4);     // 6.4 MB layer-1 output
  int*   counts = (int*)alloc((size_t)n*4);
  int*   indptr = (int*)alloc((size_t)(n+1)*4);
  int*   rank   = (int*)alloc((size_t)e*4);
  int*   csr    = (int*)alloc((size_t)e*4);
  int*   flags  = (int*)alloc((size_t)1024*4);

  int nblk = (n + 255) / 256;    // 196
  int ntiles = (n + 127) / 128;  // 391
  (void)hipMemsetAsync(counts, 0, (size_t)n*4, stream);
  (void)hipMemsetAsync(flags, 0xFF, (size_t)nblk*4, stream);   // -1 sentinels

  // layer-1 GEMM with fused CSR count (y==0, x<96 slice — dispatches first,
  // runs concurrently with the GEMM blocks that backfill)
  gemm_kernel<64,true><<<dim3(ntiles,5), 256, 0, stream>>>(
      x, W1l, b1l, W1r, b1r, xl, xr, n, src, dst, counts, rank, e);
  scan_fused_kernel<<<nblk, 256, 0, stream>>>(counts, indptr, flags, n);
  scatter_kernel<<<(e+255)/256, 256, 0, stream>>>(src, dst, rank, indptr, csr, e);

  edge_kernel<<<(n+3)/4, 256, 0, stream>>>(xl, xr, att1, bias1, indptr, csr, h, n, 1);
  // layer 2
  gemm_kernel<32,false><<<dim3(ntiles,4), 256, 0, stream>>>(
      h, W2l, b2l, W2r, b2r, xl, xr, n, nullptr, nullptr, nullptr, nullptr, 0);
  edge_kernel<<<(n+3)/4, 256, 0, stream>>>(xl, xr, att2, bias2, indptr, csr, (float*)d_out, n, 0);
}

// Round 17
// 332.535 us; speedup vs baseline: 3.7529x; 3.7529x over previous
//
#include <hip/hip_runtime.h>
#include <math.h>

// GATv2 2-layer: N=50000, E=800000, HEADS=8, C=32, ODIM=256, IN_C=64
#define HEADS 8
#define CDIM 32
#define ODIM 256

typedef _Float16 h2 __attribute__((ext_vector_type(2)));
typedef _Float16 h4 __attribute__((ext_vector_type(4)));
union H4 { h4 v; h2 p[2]; };   // edge kernel only (VGPR 20, proven no-spill)

#if __has_builtin(__builtin_amdgcn_fdot2)
#define FDOT2(a,b,c) __builtin_amdgcn_fdot2((a),(b),(c),false)
#else
static __device__ __forceinline__ float fdot2_sw(h2 a, h2 b, float c){
  return fmaf((float)a.x, (float)b.x, fmaf((float)a.y, (float)b.y, c));
}
#define FDOT2(a,b,c) fdot2_sw((a),(b),(c))
#endif

__device__ __forceinline__ float lrelu(float v, float s){ return fmaxf(v, s*v); }

// ---- fused single-kernel scan (R16-proven): chained aggregate publish +
// full lookback. flags[b] starts at -1 (memset 0xFF); published word IS the
// aggregate. Block b only waits on blocks < b (dispatched earlier) -> no
// deadlock regardless of residency.
__global__ void scan_fused_kernel(const int* __restrict__ counts,
                                  int* __restrict__ indptr,
                                  int* __restrict__ flags, int n){
  __shared__ int s[256];
  __shared__ int ws[4];
  int t = threadIdx.x;
  int b = blockIdx.x;
  int i = b*256 + t;
  int v = (i < n) ? counts[i] : 0;
  s[t] = v;
  __syncthreads();
  for (int off=1; off<256; off<<=1){
    int u = (t >= off) ? s[t-off] : 0;
    __syncthreads();
    s[t] += u;
    __syncthreads();
  }
  if (t == 255) atomicExch(&flags[b], s[255]);   // publish block aggregate
  int pre = 0;
  if (t < b){                                     // b <= 195 < 256
    int f;
    do { f = __atomic_load_n((const int*)&flags[t], __ATOMIC_RELAXED); } while (f < 0);
    pre = f;
  }
#pragma unroll
  for (int off=1; off<64; off<<=1) pre += __shfl_xor(pre, off);
  if ((t & 63) == 0) ws[t >> 6] = pre;
  __syncthreads();
  int total_prev = ws[0]+ws[1]+ws[2]+ws[3];
  int excl = total_prev + s[t] - v;
  if (i < n) indptr[i] = excl;
  if (i == n-1) indptr[n] = excl + v;
}

// atomic-free scatter: csr[indptr[d] + rank] = s. Ranks per dst are a
// permutation of 0..cnt-1 -> csr[beg,end) fully written (poison-proof).
__global__ void scatter_kernel(const int* __restrict__ src, const int* __restrict__ dst,
                               const int* __restrict__ rank, const int* __restrict__ indptr,
                               int* __restrict__ csr_src, int e){
  int i = blockIdx.x*256 + threadIdx.x;
  if (i < e){
    int r = rank[i];
    if (r >= 0){
      int d = dst[i];
      csr_src[indptr[d] + r] = src[i];
    }
  }
}

// ---------------- dense GEMM: out[n,o] = sum_k X[n,k]*W[o,k] + b[o] ----------------
// R12-proven fp32 version (VGPR 116, zero scratch). LDS-tiled, l+r fused.
// Block = 128 nodes x 64 outputs, micro-tile 8x4x{l,r} (64 accumulators).
// fp16-GEMM attempts (R13-R16) all hit compiler stack-allocation -> condemned.
// Both outputs fp16. FUSE_COUNT: y==0,x<96 blocks run CSR count+rank
// concurrently (dispatch first; other y==0 blocks no-op and backfill).
template<int K, bool FUSE_COUNT>
__global__ __launch_bounds__(256, 2) void gemm_kernel(const float* __restrict__ X,
    const float* __restrict__ Wl, const float* __restrict__ bl,
    const float* __restrict__ Wr, const float* __restrict__ br,
    _Float16* __restrict__ outl, _Float16* __restrict__ outr, int n,
    const int* __restrict__ src, const int* __restrict__ dst,
    int* __restrict__ counts, int* __restrict__ rank, int e){
  if (FUSE_COUNT && blockIdx.y == 0){
    const int CB = 96;
    if (blockIdx.x < CB){
      int stride = CB*256;
      for (int i = blockIdx.x*256 + threadIdx.x; i < e; i += stride){
        int s = src[i], d = dst[i];
        int r = -1;
        if (s != d) r = atomicAdd(counts + d, 1);   // src==dst masked (PyG removes)
        rank[i] = r;
      }
    }
    return;
  }
  const int KP = K + 4;
  __shared__ float xt[128*(K+4)];
  __shared__ float wt[2][64*(K+4)];
  int t = threadIdx.x;
  int n0 = blockIdx.x*128;
  int o0 = (FUSE_COUNT ? (blockIdx.y-1) : blockIdx.y)*64;

  for (int idx = t; idx < 128*(K/4); idx += 256){
    int row = idx/(K/4), c = (idx%(K/4))*4;
    int node = n0 + row; if (node >= n) node = n-1;   // clamp; stores guarded
    *(float4*)(xt + row*KP + c) = *(const float4*)(X + (size_t)node*K + c);
  }
  for (int idx = t; idx < 64*(K/4); idx += 256){
    int row = idx/(K/4), c = (idx%(K/4))*4;
    *(float4*)(wt[0] + row*KP + c) = *(const float4*)(Wl + (size_t)(o0+row)*K + c);
    *(float4*)(wt[1] + row*KP + c) = *(const float4*)(Wr + (size_t)(o0+row)*K + c);
  }
  __syncthreads();

  int og = t & 15;          // outputs o0 + og + 16j  (j<4)
  int ng = t >> 4;          // nodes   n0 + ng + 16i  (i<8)
  float accl[8][4] = {{0.f}}, accr[8][4] = {{0.f}};

#pragma unroll 2
  for (int kk = 0; kk < K; kk += 4){
    float4 xv[8], wl4[4], wr4[4];
#pragma unroll
    for (int i=0;i<8;i++) xv[i] = *(const float4*)(xt + (ng+16*i)*KP + kk);
#pragma unroll
    for (int j=0;j<4;j++){
      wl4[j] = *(const float4*)(wt[0] + (og+16*j)*KP + kk);
      wr4[j] = *(const float4*)(wt[1] + (og+16*j)*KP + kk);
    }
#pragma unroll
    for (int i=0;i<8;i++){
#pragma unroll
      for (int j=0;j<4;j++){
        accl[i][j] = fmaf(xv[i].x, wl4[j].x, fmaf(xv[i].y, wl4[j].y,
                     fmaf(xv[i].z, wl4[j].z, fmaf(xv[i].w, wl4[j].w, accl[i][j]))));
        accr[i][j] = fmaf(xv[i].x, wr4[j].x, fmaf(xv[i].y, wr4[j].y,
                     fmaf(xv[i].z, wr4[j].z, fmaf(xv[i].w, wr4[j].w, accr[i][j]))));
      }
    }
  }

  float bvl[4], bvr[4];
#pragma unroll
  for (int j=0;j<4;j++){ bvl[j] = bl[o0+og+16*j]; bvr[j] = br[o0+og+16*j]; }
#pragma unroll
  for (int i=0;i<8;i++){
    int node = n0 + ng + 16*i;
    if (node < n){
      _Float16* pl = outl + (size_t)node*ODIM + o0 + og;
      _Float16* pr = outr + (size_t)node*ODIM + o0 + og;
#pragma unroll
      for (int j=0;j<4;j++){
        pl[16*j] = (_Float16)(accl[i][j] + bvl[j]);
        pr[16*j] = (_Float16)(accr[i][j] + bvr[j]);
      }
    }
  }
}

// ---------------- fused edge softmax + aggregate, one wave per node ----------------
// R6-proven memory structure (1 edge/iter, depth-2 guarded prefetch, h4/lane
// coalesced 512B/wave) + packed-fp16 score path (R10/R11-proven).
__global__ __launch_bounds__(256) void edge_kernel(
    const _Float16* __restrict__ xl, const _Float16* __restrict__ xr,
    const float* __restrict__ att, const float* __restrict__ bias,
    const int* __restrict__ indptr, const int* __restrict__ csr_src,
    float* __restrict__ out, int n, int act)
{
  int wid = blockIdx.x*4 + (threadIdx.x >> 6);
  if (wid >= n) return;
  int lane = threadIdx.x & 63;
  const float LOG2E = 1.44269504088896341f;

  float4 attf = *(const float4*)(att + 4*lane);
  h2 at0 = (h2){(_Float16)(attf.x*LOG2E), (_Float16)(attf.y*LOG2E)};
  h2 at1 = (h2){(_Float16)(attf.z*LOG2E), (_Float16)(attf.w*LOG2E)};
  const h2 c02 = {(_Float16)0.2f, (_Float16)0.2f};

  H4 xrh; xrh.v = *(const h4*)(xr + (size_t)wid*ODIM + 4*lane);
  H4 self; self.v = *(const h4*)(xl + (size_t)wid*ODIM + 4*lane);

  auto score = [&](const H4& c)->float{
    h2 t0 = c.p[0] + xrh.p[0];
    h2 t1 = c.p[1] + xrh.p[1];
    h2 q0 = __builtin_elementwise_max(t0, t0 * c02);
    h2 q1 = __builtin_elementwise_max(t1, t1 * c02);
    float d = FDOT2(q0, at0, FDOT2(q1, at1, 0.f));
    d += __shfl_xor(d, 1);   // reduce over the 8 lanes of this head
    d += __shfl_xor(d, 2);
    d += __shfl_xor(d, 4);
    return d;
  };

  // self-loop seeds the accumulator
  float w0 = exp2f(score(self));
  float denom = w0;
  float4 acc;
  acc.x = w0 * (float)self.v.x;
  acc.y = w0 * (float)self.v.y;
  acc.z = w0 * (float)self.v.z;
  acc.w = w0 * (float)self.v.w;

  int beg = __builtin_amdgcn_readfirstlane(indptr[wid]);
  int end = __builtin_amdgcn_readfirstlane(indptr[wid+1]);
  int cnt = end - beg;
  H4 r0, r1;
  r0.v = (h4){}; r1.v = (h4){};
  if (cnt > 0){
    int s0 = __builtin_amdgcn_readfirstlane(csr_src[beg]);
    r0.v = *(const h4*)(xl + (size_t)s0*ODIM + 4*lane);
  }
  if (cnt > 1){
    int s1 = __builtin_amdgcn_readfirstlane(csr_src[beg+1]);
    r1.v = *(const h4*)(xl + (size_t)s1*ODIM + 4*lane);
  }
  for (int k = 0; k < cnt; ++k){
    H4 cur = r0; r0 = r1;
    if (k+2 < cnt){
      int s2 = __builtin_amdgcn_readfirstlane(csr_src[beg+k+2]);
      r1.v = *(const h4*)(xl + (size_t)s2*ODIM + 4*lane);   // prefetch 2 ahead
    }
    float pe = exp2f(score(cur));
    denom += pe;
    acc.x = fmaf(pe, (float)cur.v.x, acc.x);   // v_fma_mix (single-use cvt)
    acc.y = fmaf(pe, (float)cur.v.y, acc.y);
    acc.z = fmaf(pe, (float)cur.v.z, acc.z);
    acc.w = fmaf(pe, (float)cur.v.w, acc.w);
  }
  float inv = 1.f/denom;
  float vx = acc.x*inv, vy = acc.y*inv, vz = acc.z*inv, vw = acc.w*inv;
  // mean over heads: sum lanes {l, l^8, l^16, l^32}
  vx += __shfl_xor(vx, 8);  vx += __shfl_xor(vx, 16);  vx += __shfl_xor(vx, 32);
  vy += __shfl_xor(vy, 8);  vy += __shfl_xor(vy, 16);  vy += __shfl_xor(vy, 32);
  vz += __shfl_xor(vz, 8);  vz += __shfl_xor(vz, 16);  vz += __shfl_xor(vz, 32);
  vw += __shfl_xor(vw, 8);  vw += __shfl_xor(vw, 16);  vw += __shfl_xor(vw, 32);
  if (lane < 8){
    float4 bv = *(const float4*)(bias + 4*lane);
    float ox = vx*0.125f + bv.x;
    float oy = vy*0.125f + bv.y;
    float oz = vz*0.125f + bv.z;
    float ow = vw*0.125f + bv.w;
    if (act){
      ox = lrelu(ox, 0.01f); oy = lrelu(oy, 0.01f);
      oz = lrelu(oz, 0.01f); ow = lrelu(ow, 0.01f);
    }
    *(float4*)(out + (size_t)wid*CDIM + 4*lane) = make_float4(ox, oy, oz, ow);
  }
}

extern "C" void kernel_launch(void* const* d_in, const int* in_sizes, int n_in,
                              void* d_out, int out_size, void* d_ws, size_t ws_size,
                              hipStream_t stream){
  (void)n_in; (void)out_size; (void)ws_size;
  const float* x    = (const float*)d_in[0];
  const int*   ei   = (const int*)d_in[1];
  const float* W1l  = (const float*)d_in[2];
  const float* b1l  = (const float*)d_in[3];
  const float* W1r  = (const float*)d_in[4];
  const float* b1r  = (const float*)d_in[5];
  const float* att1 = (const float*)d_in[6];
  const float* bias1= (const float*)d_in[7];
  const float* W2l  = (const float*)d_in[8];
  const float* b2l  = (const float*)d_in[9];
  const float* W2r  = (const float*)d_in[10];
  const float* b2r  = (const float*)d_in[11];
  const float* att2 = (const float*)d_in[12];
  const float* bias2= (const float*)d_in[13];
  int n = in_sizes[0] / 64;   // 50000
  int e = in_sizes[1] / 2;    // 800000
  const int* src = ei;
  const int* dst = ei + e;

  char* ws = (char*)d_ws;
  size_t off = 0;
  auto alloc = [&](size_t bytes)->char*{
    char* p = ws + off; off += (bytes + 255) & ~(size_t)255; return p;
  };
  _Float16* xl  = (_Float16*)alloc((size_t)n*ODIM*2);  // 25.6 MB fp16
  _Float16* xr  = (_Float16*)alloc((size_t)n*ODIM*2);  // 25.6 MB fp16
  float* h      = (float*)alloc((size_t)n*CDIM*4);     // 6.4 MB layer-1 output
  int*   counts = (int*)alloc((size_t)n*4);
  int*   indptr = (int*)alloc((size_t)(n+1)*4);
  int*   rank   = (int*)alloc((size_t)e*4);
  int*   csr    = (int*)alloc((size_t)e*4);
  int*   flags  = (int*)alloc((size_t)1024*4);

  int nblk = (n + 255) / 256;    // 196
  int ntiles = (n + 127) / 128;  // 391
  (void)hipMemsetAsync(counts, 0, (size_t)n*4, stream);
  (void)hipMemsetAsync(flags, 0xFF, (size_t)nblk*4, stream);   // -1 sentinels

  // layer-1 GEMM with fused CSR count (y==0, x<96 slice — dispatches first,
  // runs concurrently with the GEMM blocks that backfill)
  gemm_kernel<64,true><<<dim3(ntiles,5), 256, 0, stream>>>(
      x, W1l, b1l, W1r, b1r, xl, xr, n, src, dst, counts, rank, e);
  scan_fused_kernel<<<nblk, 256, 0, stream>>>(counts, indptr, flags, n);
  scatter_kernel<<<(e+255)/256, 256, 0, stream>>>(src, dst, rank, indptr, csr, e);

  edge_kernel<<<(n+3)/4, 256, 0, stream>>>(xl, xr, att1, bias1, indptr, csr, h, n, 1);
  // layer 2
  gemm_kernel<32,false><<<dim3(ntiles,4), 256, 0, stream>>>(
      h, W2l, b2l, W2r, b2r, xl, xr, n, nullptr, nullptr, nullptr, nullptr, 0);
  edge_kernel<<<(n+3)/4, 256, 0, stream>>>(xl, xr, att2, bias2, indptr, csr, (float*)d_out, n, 0);
}